// Round 1
// baseline (744.051 us; speedup 1.0000x reference)
//
#include <hip/hip_runtime.h>
#include <hip/hip_bf16.h>
#include <math.h>

// QuantumLLM fused pipeline, round 1 (correctness-first, MFMA everywhere).
//
// Pipeline: x -> [GEMM+gelu] g -> [LN+phase] u -> [GEMM] qkvo(q,k,v_r,v_i)
//           -> per batch: S=q k^T -> softmax -> O = P [v_r|v_i]  -> [GEMM] out split.
// Algebra: qkv_in = [r,i,r,i,r,i] => fold qkv_w K 3072->1024; keep only 4/6 out blocks.
//          coll == 1 always (amp <= sqrt(1/512)+eps < 0.1), excitation is a constant table.

#define TWO_PI_F 6.283185307179586f

typedef __attribute__((ext_vector_type(4))) float f32x4;
typedef __attribute__((ext_vector_type(8))) short bf16x8;
typedef __hip_bfloat16 bf16;

__device__ __forceinline__ void gl_lds16(const void* g, void* l) {
  __builtin_amdgcn_global_load_lds((const __attribute__((address_space(1))) void*)g,
                                   (__attribute__((address_space(3))) void*)l, 16, 0, 0);
}

// ---------------- GEMM: C = epi(A * B^T * scale + bias) ----------------
// A: M x K (lda), B: N x K (ldb), both bf16 row-major. 128x128 tile, BK=32,
// 4 waves 2x2, each wave 64x64 = 4x4 mfma_f32_16x16x32_bf16 tiles.
// EPI: 0 = bias+store bf16; 1 = bias+gelu bf16; 2 = scale, store bf16; 3 = bias, split fp32 store.
template <int EPI>
__global__ __launch_bounds__(256, 2) void gemm_bt(
    const bf16* __restrict__ A, const bf16* __restrict__ B, void* __restrict__ C,
    float* __restrict__ C2, const float* __restrict__ bias, int M, int N, int K,
    int lda, int ldb, int ldc, float scale) {
  __shared__ __align__(16) bf16 sA[128 * 32];
  __shared__ __align__(16) bf16 sB[128 * 32];
  const int tid = threadIdx.x;
  const int lane = tid & 63;
  const int wid = tid >> 6;
  const int wm = wid >> 1, wn = wid & 1;
  const int bm = blockIdx.y * 128, bn = blockIdx.x * 128;

  f32x4 zero = {0.f, 0.f, 0.f, 0.f};
  f32x4 acc[4][4];
#pragma unroll
  for (int i = 0; i < 4; ++i)
#pragma unroll
    for (int j = 0; j < 4; ++j) acc[i][j] = zero;

  const int c0 = tid, c1 = tid + 256;
  const int ra0 = c0 >> 2, sa0 = (c0 & 3) << 3;
  const int ra1 = c1 >> 2, sa1 = (c1 & 3) << 3;
  const int fr = lane & 15, ksl = lane >> 4;

  const long long rowA0 = (long long)(bm + ra0) * lda;
  const long long rowA1 = (long long)(bm + ra1) * lda;
  const long long rowB0 = (long long)(bn + ra0) * ldb;
  const long long rowB1 = (long long)(bn + ra1) * ldb;

  for (int k0 = 0; k0 < K; k0 += 32) {
    gl_lds16(A + rowA0 + k0 + sa0, &sA[c0 * 8]);
    gl_lds16(A + rowA1 + k0 + sa1, &sA[c1 * 8]);
    gl_lds16(B + rowB0 + k0 + sa0, &sB[c0 * 8]);
    gl_lds16(B + rowB1 + k0 + sa1, &sB[c1 * 8]);
    __syncthreads();
    bf16x8 af[4], bfv[4];
#pragma unroll
    for (int i = 0; i < 4; ++i)
      af[i] = *(const bf16x8*)&sA[(wm * 64 + i * 16 + fr) * 32 + ksl * 8];
#pragma unroll
    for (int j = 0; j < 4; ++j)
      bfv[j] = *(const bf16x8*)&sB[(wn * 64 + j * 16 + fr) * 32 + ksl * 8];
#pragma unroll
    for (int i = 0; i < 4; ++i)
#pragma unroll
      for (int j = 0; j < 4; ++j)
        acc[i][j] = __builtin_amdgcn_mfma_f32_16x16x32_bf16(af[i], bfv[j], acc[i][j], 0, 0, 0);
    __syncthreads();
  }

#pragma unroll
  for (int i = 0; i < 4; ++i)
#pragma unroll
    for (int j = 0; j < 4; ++j)
#pragma unroll
      for (int r = 0; r < 4; ++r) {
        const int row = bm + wm * 64 + i * 16 + ksl * 4 + r;
        const int col = bn + wn * 64 + j * 16 + fr;
        float v = acc[i][j][r] * scale;
        if (bias) v += bias[col];
        if constexpr (EPI == 1) {
          const float t = v;
          v = 0.5f * t * (1.0f + tanhf(0.7978845608028654f * (t + 0.044715f * t * t * t)));
        }
        if constexpr (EPI == 3) {
          float* dst = (col < 512) ? (float*)C : C2;
          dst[(long long)row * 512 + (col & 511)] = v;
        } else {
          ((bf16*)C)[(long long)row * ldc + col] = __float2bfloat16(v);
        }
      }
  (void)M;
  (void)N;
}

// ---------------- LayerNorm + phase ops: g(row,1024) -> u(row,1024) ----------------
__global__ __launch_bounds__(256) void ln_phase_kernel(
    const bf16* __restrict__ g, bf16* __restrict__ u, const float* __restrict__ ln_g,
    const float* __restrict__ ln_b, const float* __restrict__ lcos,
    const float* __restrict__ lsin, const float* __restrict__ cost,
    const float* __restrict__ sint) {
  __shared__ float sg[1024];
  __shared__ float red[4];
  const int tid = threadIdx.x;
  const int lane = tid & 63, wid = tid >> 6;
  const long long row = blockIdx.x;
  const bf16* gr = g + row * 1024;

  float lsum = 0.f;
#pragma unroll
  for (int k = 0; k < 4; ++k) {
    const float v = __bfloat162float(gr[tid + k * 256]);
    sg[tid + k * 256] = v;
    lsum += v;
  }
#pragma unroll
  for (int off = 32; off > 0; off >>= 1) lsum += __shfl_xor(lsum, off);
  if (lane == 0) red[wid] = lsum;
  __syncthreads();
  const float mu = (red[0] + red[1] + red[2] + red[3]) * (1.0f / 1024.0f);
  __syncthreads();
  float lvar = 0.f;
#pragma unroll
  for (int k = 0; k < 4; ++k) {
    const float d = sg[tid + k * 256] - mu;
    lvar += d * d;
  }
#pragma unroll
  for (int off = 32; off > 0; off >>= 1) lvar += __shfl_xor(lvar, off);
  if (lane == 0) red[wid] = lvar;
  __syncthreads();
  const float var = (red[0] + red[1] + red[2] + red[3]) * (1.0f / 1024.0f);
  const float rs = rsqrtf(var + 1e-5f);

#pragma unroll
  for (int kk = 0; kk < 2; ++kk) {
    const int p = tid + kk * 256;
    const float rp = (sg[p] - mu) * rs * ln_g[p] + ln_b[p];
    const float ip = (sg[p + 512] - mu) * rs * ln_g[p + 512] + ln_b[p + 512];
    const float ang = atan2f(ip + 1e-8f, rp + 1e-8f);
    int idx = (int)((ang / TWO_PI_F) * 1023.0f);  // trunc toward zero, like astype(int32)
    idx = idx < 0 ? idx + 1024 : idx;             // jnp.mod(.., 1024)
    float real = rp * cost[idx];
    float imag = ip * sint[idx];
    const float nrm = rsqrtf(real * real + imag * imag + 1e-8f) * 0.044194173824159216f;
    real *= nrm;
    imag *= nrm;
    const float amp = sqrtf(real * real + imag * imag + 1e-8f);
    const float coll = (amp < 0.1f) ? 1.0f : 0.0f;  // always 1.0 in practice; keep faithful
    real += coll * lcos[p];
    imag += coll * lsin[p];
    const float n2 = rsqrtf(real * real + imag * imag + 1e-8f);
    u[row * 1024 + p] = __float2bfloat16(real * n2);
    u[row * 1024 + 512 + p] = __float2bfloat16(imag * n2);
  }
}

// ---------------- rowwise softmax in place on bf16 scores (row = 4096) ----------------
__global__ __launch_bounds__(256) void softmax_kernel(bf16* __restrict__ s) {
  __shared__ float ss[4096];
  __shared__ float red[4];
  const int tid = threadIdx.x;
  const int lane = tid & 63, wid = tid >> 6;
  bf16* sr = s + (long long)blockIdx.x * 4096;
  float mx = -3.0e38f;
#pragma unroll
  for (int k = 0; k < 16; ++k) {
    const float v = __bfloat162float(sr[tid + k * 256]);
    ss[tid + k * 256] = v;
    mx = fmaxf(mx, v);
  }
#pragma unroll
  for (int off = 32; off > 0; off >>= 1) mx = fmaxf(mx, __shfl_xor(mx, off));
  if (lane == 0) red[wid] = mx;
  __syncthreads();
  mx = fmaxf(fmaxf(red[0], red[1]), fmaxf(red[2], red[3]));
  __syncthreads();
  float sum = 0.f;
#pragma unroll
  for (int k = 0; k < 16; ++k) {
    const float e = expf(ss[tid + k * 256] - mx);
    ss[tid + k * 256] = e;
    sum += e;
  }
#pragma unroll
  for (int off = 32; off > 0; off >>= 1) sum += __shfl_xor(sum, off);
  if (lane == 0) red[wid] = sum;
  __syncthreads();
  const float inv = 1.0f / (red[0] + red[1] + red[2] + red[3]);
#pragma unroll
  for (int k = 0; k < 16; ++k) sr[tid + k * 256] = __float2bfloat16(ss[tid + k * 256] * inv);
}

// ---------------- V transpose: qkvo[:, 1024:2048] (16384x1024) -> vT[4][1024][4096] ----------------
__global__ __launch_bounds__(256) void transpose_v(const bf16* __restrict__ qkvo,
                                                   bf16* __restrict__ vT) {
  __shared__ bf16 tile[32][33];
  const int b = blockIdx.z;
  const int m0 = blockIdx.x * 32;
  const int d0 = blockIdx.y * 32;
  const int tx = threadIdx.x & 31, ty = threadIdx.x >> 5;
#pragma unroll
  for (int k = 0; k < 4; ++k) {
    const int r = ty + k * 8;
    tile[r][tx] = qkvo[(long long)(b * 4096 + m0 + r) * 2048 + 1024 + d0 + tx];
  }
  __syncthreads();
#pragma unroll
  for (int k = 0; k < 4; ++k) {
    const int r = ty + k * 8;
    vT[((long long)b * 1024 + d0 + r) * 4096 + m0 + tx] = tile[tx][r];
  }
}

// ---------------- prep ----------------
__global__ void cast_f2b(const float* __restrict__ in, bf16* __restrict__ out, long long n) {
  long long i = (long long)blockIdx.x * blockDim.x + threadIdx.x;
  const long long stride = (long long)gridDim.x * blockDim.x;
  for (; i < n; i += stride) out[i] = __float2bfloat16(in[i]);
}

// W_eff rows: [0,512)=q_r (qkv rows 0:512), [512,1024)=k_r (rows 1024:1536),
// [1024,1536)=v_r (rows 2048:2560), [1536,2048)=v_i (rows 2560:3072).
// W_eff[o,j] = sum_c qkv_w[so, j + 1024*c].
__global__ void fold_qkv(const float* __restrict__ w, const float* __restrict__ b,
                         bf16* __restrict__ weff, float* __restrict__ beff) {
  const int i = blockIdx.x * blockDim.x + threadIdx.x;
  if (i < 2048 * 1024) {
    const int o = i >> 10, j = i & 1023;
    const int so = (o < 512) ? o : (o < 1024 ? o + 512 : o + 1024);
    const float* wr = w + (long long)so * 3072;
    weff[i] = __float2bfloat16(wr[j] + wr[1024 + j] + wr[2048 + j]);
    if (j == 0) beff[o] = b[so];
  }
}

__global__ void tables_kernel(float* __restrict__ cost, float* __restrict__ sint,
                              float* __restrict__ lcos, float* __restrict__ lsin,
                              const float* __restrict__ exc) {
  const int i = blockIdx.x * blockDim.x + threadIdx.x;
  const double step = 6.283185307179586 / 1023.0;
  if (i < 1024) {
    const float a = (float)((double)i * step);
    cost[i] = cosf(a);
    sint[i] = sinf(a);
  }
  if (i < 512) {
    const float el = ((float)i / 511.0f) * TWO_PI_F;
    const float m = fmodf(el, TWO_PI_F);
    int li = (int)((m / TWO_PI_F) * 1024.0f);
    li = min(max(li, 0), 1023);
    const float a = (float)((double)li * step);
    lcos[i] = cosf(a) * exc[0];
    lsin[i] = sinf(a) * exc[0];
  }
}

extern "C" void kernel_launch(void* const* d_in, const int* in_sizes, int n_in, void* d_out,
                              int out_size, void* d_ws, size_t ws_size, hipStream_t stream) {
  const float* x = (const float*)d_in[0];
  const float* ft_w = (const float*)d_in[1];
  const float* ft_b = (const float*)d_in[2];
  const float* ln_g = (const float*)d_in[3];
  const float* ln_b = (const float*)d_in[4];
  const float* exc = (const float*)d_in[5];
  const float* qkv_w = (const float*)d_in[6];
  const float* qkv_b = (const float*)d_in[7];
  const float* op_w = (const float*)d_in[8];
  const float* op_b = (const float*)d_in[9];

  char* ws = (char*)d_ws;
  const size_t MB = 1024ull * 1024ull;
  // footprint 184 MB with liveness overlap (sc reuses x_b+g, obuf reuses u).
  bf16* ftw_b = (bf16*)(ws + 0);                       // 1 MB
  bf16* weff = (bf16*)(ws + 1 * MB);                   // 4 MB
  bf16* opw_b = (bf16*)(ws + 5 * MB);                  // 2 MB
  float* beff = (float*)(ws + 7 * MB);                 // 8 KB
  float* cost = (float*)(ws + 7 * MB + 16384);         // 4 KB
  float* sint = (float*)(ws + 7 * MB + 16384 + 4096);  // 4 KB
  float* lcos = (float*)(ws + 7 * MB + 16384 + 8192);  // 2 KB
  float* lsin = (float*)(ws + 7 * MB + 16384 + 8192 + 2048);
  bf16* x_b = (bf16*)(ws + 8 * MB);    // 16 MB, dead after stage-A GEMM
  bf16* gbuf = (bf16*)(ws + 24 * MB);  // 32 MB, dead after LN
  bf16* ubuf = (bf16*)(ws + 56 * MB);  // 32 MB, dead after QKV GEMM
  bf16* qkvo = (bf16*)(ws + 88 * MB);  // 64 MB
  bf16* vT = (bf16*)(ws + 152 * MB);   // 32 MB
  bf16* sc = (bf16*)(ws + 8 * MB);     // 32 MB (reuse x_b+g)
  bf16* obuf = (bf16*)(ws + 56 * MB);  // 32 MB (reuse u)

  cast_f2b<<<1024, 256, 0, stream>>>(ft_w, ftw_b, 1024LL * 512);
  cast_f2b<<<1024, 256, 0, stream>>>(op_w, opw_b, 1024LL * 1024);
  cast_f2b<<<4096, 256, 0, stream>>>(x, x_b, 16384LL * 512);
  fold_qkv<<<8192, 256, 0, stream>>>(qkv_w, qkv_b, weff, beff);
  tables_kernel<<<4, 256, 0, stream>>>(cost, sint, lcos, lsin, exc);

  // stage A: g = gelu(x @ ft_w^T + ft_b)
  gemm_bt<1><<<dim3(8, 128), 256, 0, stream>>>(x_b, ftw_b, gbuf, nullptr, ft_b, 16384, 1024,
                                               512, 512, 512, 1024, 1.0f);
  // LN + phase -> u
  ln_phase_kernel<<<16384, 256, 0, stream>>>(gbuf, ubuf, ln_g, ln_b, lcos, lsin, cost, sint);
  // qkvo = u @ W_eff^T + b_eff   (cols: q 0:512, k 512:1024, v_r 1024:1536, v_i 1536:2048)
  gemm_bt<0><<<dim3(16, 128), 256, 0, stream>>>(ubuf, weff, qkvo, nullptr, beff, 16384, 2048,
                                                1024, 1024, 1024, 2048, 1.0f);
  transpose_v<<<dim3(128, 32, 4), 256, 0, stream>>>(qkvo, vT);

  for (int b = 0; b < 4; ++b) {
    const bf16* qb = qkvo + (long long)b * 4096 * 2048;
    // S = (q k^T) * D^-0.5
    gemm_bt<2><<<dim3(32, 32), 256, 0, stream>>>(qb, qb + 512, sc, nullptr, nullptr, 4096,
                                                 4096, 512, 2048, 2048, 4096,
                                                 0.04419417382415922f);
    softmax_kernel<<<4096, 256, 0, stream>>>(sc);
    // O = P @ [v_r | v_i]  via vT (A.B^T form)
    gemm_bt<0><<<dim3(8, 32), 256, 0, stream>>>(sc, vT + (long long)b * 1024 * 4096,
                                                obuf + (long long)b * 4096 * 1024, nullptr,
                                                nullptr, 4096, 1024, 4096, 4096, 4096, 1024,
                                                1.0f);
  }
  // out = o @ op_w^T + op_b, split halves into d_out
  gemm_bt<3><<<dim3(8, 128), 256, 0, stream>>>(obuf, opw_b, d_out, (float*)d_out + 8388608LL,
                                               op_b, 16384, 1024, 1024, 1024, 1024, 0, 1.0f);
  (void)in_sizes;
  (void)n_in;
  (void)out_size;
  (void)ws_size;
}

// Round 2
// 610.667 us; speedup vs baseline: 1.2184x; 1.2184x over previous
//
#include <hip/hip_runtime.h>
#include <hip/hip_bf16.h>
#include <math.h>

// QuantumLLM fused pipeline, round 2.
// Algebra: (1) qkv_in = [r,i,r,i,r,i] => fold qkv_w K 3072->1024, keep 4/6 blocks.
//          (2) coll == 1 always (amp <= sqrt(1/512)+eps < 0.1) => excitation is a const table.
//          (3) softmax rows sum to 1 => out = P·(V@op_w^T) + op_b, and V@op_w^T = u@(op_w·W_v)^T
//              => fold op_w into the QKV weight; final GEMM eliminated; PV writes d_out.
// Structure: x ->[GEMM+gelu] g ->[LN+phase] u ->[GEMM, v2 written transposed] qk,v2T
//            -> pairs of batches: S=q k^T (z=2) -> softmax -> out=P·V2 + op_b (z=2, fp32 split).

#define TWO_PI_F 6.283185307179586f

typedef __attribute__((ext_vector_type(4))) float f32x4;
typedef __attribute__((ext_vector_type(8))) short bf16x8;
typedef __attribute__((ext_vector_type(4))) unsigned short u16x4;
typedef __hip_bfloat16 bf16;

__device__ __forceinline__ void gl_lds16(const void* g, void* l) {
  __builtin_amdgcn_global_load_lds((const __attribute__((address_space(1))) void*)g,
                                   (__attribute__((address_space(3))) void*)l, 16, 0, 0);
}
__device__ __forceinline__ unsigned short f2bf_bits(float f) {
  union { __hip_bfloat16 h; unsigned short u; } cv;
  cv.h = __float2bfloat16(f);
  return cv.u;
}
__device__ __forceinline__ float bf_bits2f(unsigned short b) {
  union { unsigned int u; float f; } cv;
  cv.u = ((unsigned int)b) << 16;
  return cv.f;
}

// ---------------- GEMM: C = epi(A * B^T * scale + bias) ----------------
// A: M x K (lda), B: N x K (ldb), bf16 row-major. 128x128 tile, BK=32, 4 waves 2x2.
// EPI: 0 bias+store bf16; 1 bias+gelu bf16; 2 scale bf16; 3 bias, split fp32 (d_out);
//      4 qkv: col<1024 -> C (qk, ldc), col>=1024 -> Cx transposed v2T packed 8B stores.
// z batching: A += z*zsa, B += z*zsb; EPI 0/1/2: C += z*zsc elems; EPI 3: row += z*zsc.
template <int EPI>
__global__ __launch_bounds__(256, 2) void gemm_bt(
    const bf16* __restrict__ A, const bf16* __restrict__ B, void* __restrict__ C,
    void* __restrict__ Cx, const float* __restrict__ bias, int K, int lda, int ldb, int ldc,
    float scale, long long zsa, long long zsb, long long zsc) {
  __shared__ __align__(16) bf16 sA[128 * 32];
  __shared__ __align__(16) bf16 sB[128 * 32];
  const int tid = threadIdx.x;
  const int lane = tid & 63;
  const int wid = tid >> 6;
  const int wm = wid >> 1, wn = wid & 1;
  const int bm = blockIdx.y * 128, bn = blockIdx.x * 128;
  const int z = blockIdx.z;
  const bf16* Az = A + (long long)z * zsa;
  const bf16* Bz = B + (long long)z * zsb;

  f32x4 zero = {0.f, 0.f, 0.f, 0.f};
  f32x4 acc[4][4];
#pragma unroll
  for (int i = 0; i < 4; ++i)
#pragma unroll
    for (int j = 0; j < 4; ++j) acc[i][j] = zero;

  const int c0 = tid, c1 = tid + 256;
  const int ra0 = c0 >> 2, sa0 = (c0 & 3) << 3;
  const int ra1 = c1 >> 2, sa1 = (c1 & 3) << 3;
  const int fr = lane & 15, ksl = lane >> 4;

  const long long rowA0 = (long long)(bm + ra0) * lda;
  const long long rowA1 = (long long)(bm + ra1) * lda;
  const long long rowB0 = (long long)(bn + ra0) * ldb;
  const long long rowB1 = (long long)(bn + ra1) * ldb;

  for (int k0 = 0; k0 < K; k0 += 32) {
    gl_lds16(Az + rowA0 + k0 + sa0, &sA[c0 * 8]);
    gl_lds16(Az + rowA1 + k0 + sa1, &sA[c1 * 8]);
    gl_lds16(Bz + rowB0 + k0 + sa0, &sB[c0 * 8]);
    gl_lds16(Bz + rowB1 + k0 + sa1, &sB[c1 * 8]);
    __syncthreads();
    bf16x8 af[4], bfv[4];
#pragma unroll
    for (int i = 0; i < 4; ++i)
      af[i] = *(const bf16x8*)&sA[(wm * 64 + i * 16 + fr) * 32 + ksl * 8];
#pragma unroll
    for (int j = 0; j < 4; ++j)
      bfv[j] = *(const bf16x8*)&sB[(wn * 64 + j * 16 + fr) * 32 + ksl * 8];
#pragma unroll
    for (int i = 0; i < 4; ++i)
#pragma unroll
      for (int j = 0; j < 4; ++j)
        acc[i][j] = __builtin_amdgcn_mfma_f32_16x16x32_bf16(af[i], bfv[j], acc[i][j], 0, 0, 0);
    __syncthreads();
  }

#pragma unroll
  for (int i = 0; i < 4; ++i)
#pragma unroll
    for (int j = 0; j < 4; ++j) {
      const int row0 = bm + wm * 64 + i * 16 + ksl * 4;
      const int col = bn + wn * 64 + j * 16 + fr;
      float v[4];
#pragma unroll
      for (int r = 0; r < 4; ++r) {
        v[r] = acc[i][j][r] * scale;
        if (bias) v[r] += bias[col];
        if constexpr (EPI == 1) {
          const float t = v[r];
          float y = 0.7978845608028654f * (t + 0.044715f * t * t * t);
          y = fminf(fmaxf(y, -15.f), 15.f);
          const float e = __expf(2.f * y);
          v[r] = t * e / (1.f + e);  // 0.5*t*(1+tanh(y))
        }
      }
      if constexpr (EPI == 3) {
        const int rowz = row0 + z * (int)zsc;
        float* dst = (col < 512) ? (float*)C : (float*)Cx;
#pragma unroll
        for (int r = 0; r < 4; ++r) dst[(long long)(rowz + r) * 512 + (col & 511)] = v[r];
      } else if constexpr (EPI == 4) {
        if (col < 1024) {
          bf16* cc = (bf16*)C;
#pragma unroll
          for (int r = 0; r < 4; ++r)
            cc[(long long)(row0 + r) * ldc + col] = __float2bfloat16(v[r]);
        } else {
          const int d = col - 1024;
          const int b = row0 >> 12, mm = row0 & 4095;
          u16x4 w;
#pragma unroll
          for (int r = 0; r < 4; ++r) w[r] = f2bf_bits(v[r]);
          *(u16x4*)((unsigned short*)Cx + ((long long)(b * 1024 + d)) * 4096 + mm) = w;
        }
      } else {
        bf16* cc = (bf16*)C + (long long)z * zsc;
#pragma unroll
        for (int r = 0; r < 4; ++r) cc[(long long)(row0 + r) * ldc + col] = __float2bfloat16(v[r]);
      }
    }
}

// ---------------- LayerNorm + phase ops: g(row,1024) -> u(row,1024) ----------------
__global__ __launch_bounds__(256) void ln_phase_kernel(
    const bf16* __restrict__ g, bf16* __restrict__ u, const float* __restrict__ ln_g,
    const float* __restrict__ ln_b, const float* __restrict__ lcos,
    const float* __restrict__ lsin, const float* __restrict__ cost,
    const float* __restrict__ sint) {
  __shared__ float sg[1024];
  __shared__ float red[4];
  const int tid = threadIdx.x;
  const int lane = tid & 63, wid = tid >> 6;
  const long long row = blockIdx.x;
  const bf16* gr = g + row * 1024;

  const u16x4 raw = *(const u16x4*)(gr + tid * 4);
  float lv[4];
  float lsum = 0.f;
#pragma unroll
  for (int e = 0; e < 4; ++e) {
    lv[e] = bf_bits2f(raw[e]);
    lsum += lv[e];
  }
  *(f32x4*)&sg[tid * 4] = *(f32x4*)lv;
#pragma unroll
  for (int off = 32; off > 0; off >>= 1) lsum += __shfl_xor(lsum, off);
  if (lane == 0) red[wid] = lsum;
  __syncthreads();
  const float mu = (red[0] + red[1] + red[2] + red[3]) * (1.0f / 1024.0f);
  __syncthreads();
  float lvar = 0.f;
#pragma unroll
  for (int e = 0; e < 4; ++e) {
    const float d = lv[e] - mu;
    lvar += d * d;
  }
#pragma unroll
  for (int off = 32; off > 0; off >>= 1) lvar += __shfl_xor(lvar, off);
  if (lane == 0) red[wid] = lvar;
  __syncthreads();
  const float var = (red[0] + red[1] + red[2] + red[3]) * (1.0f / 1024.0f);
  const float rs = rsqrtf(var + 1e-5f);

#pragma unroll
  for (int kk = 0; kk < 2; ++kk) {
    const int p = tid + kk * 256;
    const float rp = (sg[p] - mu) * rs * ln_g[p] + ln_b[p];
    const float ip = (sg[p + 512] - mu) * rs * ln_g[p + 512] + ln_b[p + 512];
    const float ang = atan2f(ip + 1e-8f, rp + 1e-8f);
    int idx = (int)((ang / TWO_PI_F) * 1023.0f);  // trunc toward zero, like astype(int32)
    idx = idx < 0 ? idx + 1024 : idx;             // jnp.mod(.., 1024)
    float real = rp * cost[idx];
    float imag = ip * sint[idx];
    const float nrm = rsqrtf(real * real + imag * imag + 1e-8f) * 0.044194173824159216f;
    real *= nrm;
    imag *= nrm;
    const float amp = sqrtf(real * real + imag * imag + 1e-8f);
    const float coll = (amp < 0.1f) ? 1.0f : 0.0f;  // always 1.0 in practice; keep faithful
    real += coll * lcos[p];
    imag += coll * lsin[p];
    const float n2 = rsqrtf(real * real + imag * imag + 1e-8f);
    u[row * 1024 + p] = __float2bfloat16(real * n2);
    u[row * 1024 + 512 + p] = __float2bfloat16(imag * n2);
  }
}

// ---------------- rowwise softmax in place on bf16 scores (row = 4096) ----------------
__global__ __launch_bounds__(256) void softmax_kernel(bf16* __restrict__ s) {
  __shared__ float ss[4096];
  __shared__ float red[4];
  const int tid = threadIdx.x;
  const int lane = tid & 63, wid = tid >> 6;
  bf16* sr = s + (long long)blockIdx.x * 4096;
  float mx = -3.0e38f;
#pragma unroll
  for (int k = 0; k < 4; ++k) {
    const int base = (k * 256 + tid) * 4;
    const u16x4 raw = *(const u16x4*)(sr + base);
    f32x4 f;
#pragma unroll
    for (int e = 0; e < 4; ++e) {
      f[e] = bf_bits2f(raw[e]);
      mx = fmaxf(mx, f[e]);
    }
    *(f32x4*)&ss[base] = f;
  }
#pragma unroll
  for (int off = 32; off > 0; off >>= 1) mx = fmaxf(mx, __shfl_xor(mx, off));
  if (lane == 0) red[wid] = mx;
  __syncthreads();
  mx = fmaxf(fmaxf(red[0], red[1]), fmaxf(red[2], red[3]));
  __syncthreads();
  float sum = 0.f;
#pragma unroll
  for (int k = 0; k < 4; ++k) {
    const int base = (k * 256 + tid) * 4;
    f32x4 f = *(f32x4*)&ss[base];
#pragma unroll
    for (int e = 0; e < 4; ++e) {
      f[e] = __expf(f[e] - mx);
      sum += f[e];
    }
    *(f32x4*)&ss[base] = f;
  }
#pragma unroll
  for (int off = 32; off > 0; off >>= 1) sum += __shfl_xor(sum, off);
  if (lane == 0) red[wid] = sum;
  __syncthreads();
  const float inv = 1.0f / (red[0] + red[1] + red[2] + red[3]);
#pragma unroll
  for (int k = 0; k < 4; ++k) {
    const int base = (k * 256 + tid) * 4;
    const f32x4 f = *(f32x4*)&ss[base];
    u16x4 w;
#pragma unroll
    for (int e = 0; e < 4; ++e) w[e] = f2bf_bits(f[e] * inv);
    *(u16x4*)(sr + base) = w;
  }
}

// ---------------- prep ----------------
__global__ void cast4_f2b(const float* __restrict__ in, bf16* __restrict__ out, long long n4) {
  long long i = (long long)blockIdx.x * blockDim.x + threadIdx.x;
  const long long stride = (long long)gridDim.x * blockDim.x;
  for (; i < n4; i += stride) {
    const f32x4 f = *(const f32x4*)(in + i * 4);
    u16x4 w;
#pragma unroll
    for (int e = 0; e < 4; ++e) w[e] = f2bf_bits(f[e]);
    *(u16x4*)((unsigned short*)out + i * 4) = w;
  }
}

// weff rows [0,512)=q (qkv rows 0:512), [512,1024)=k (rows 1024:1536);
// wvT[j,t] = W_v[t,j] = sum_c qkv_w[2048+t, j+1024c]  (v_r rows 2048:2560, v_i 2560:3072).
__global__ void fold_qkv(const float* __restrict__ w, const float* __restrict__ b,
                         bf16* __restrict__ weff, bf16* __restrict__ wvT,
                         float* __restrict__ beff) {
  const int i = blockIdx.x * blockDim.x + threadIdx.x;
  if (i < 2048 * 1024) {
    const int o = i >> 10, j = i & 1023;
    if (o < 1024) {
      const int so = (o < 512) ? o : o + 512;
      const float* wr = w + (long long)so * 3072;
      weff[i] = __float2bfloat16(wr[j] + wr[1024 + j] + wr[2048 + j]);
      if (j == 0) beff[o] = b[so];
    } else {
      const int t = o - 1024;
      const float* wr = w + (long long)(2048 + t) * 3072;
      wvT[(long long)j * 1024 + t] = __float2bfloat16(wr[j] + wr[1024 + j] + wr[2048 + j]);
    }
  }
}

// beff[1024+o] = sum_t op_w[o,t] * qkv_b[2048+t]
__global__ void bias_fold(const float* __restrict__ op_w, const float* __restrict__ qkv_b,
                          float* __restrict__ beff) {
  const int o = blockIdx.x * blockDim.x + threadIdx.x;
  if (o < 1024) {
    const float* wr = op_w + (long long)o * 1024;
    float s = 0.f;
    for (int t = 0; t < 1024; ++t) s += wr[t] * qkv_b[2048 + t];
    beff[1024 + o] = s;
  }
}

__global__ void tables_kernel(float* __restrict__ cost, float* __restrict__ sint,
                              float* __restrict__ lcos, float* __restrict__ lsin,
                              const float* __restrict__ exc) {
  const int i = blockIdx.x * blockDim.x + threadIdx.x;
  const double step = 6.283185307179586 / 1023.0;
  if (i < 1024) {
    const float a = (float)((double)i * step);
    cost[i] = cosf(a);
    sint[i] = sinf(a);
  }
  if (i < 512) {
    const float el = ((float)i / 511.0f) * TWO_PI_F;
    const float m = fmodf(el, TWO_PI_F);
    int li = (int)((m / TWO_PI_F) * 1024.0f);
    li = min(max(li, 0), 1023);
    const float a = (float)((double)li * step);
    lcos[i] = cosf(a) * exc[0];
    lsin[i] = sinf(a) * exc[0];
  }
}

extern "C" void kernel_launch(void* const* d_in, const int* in_sizes, int n_in, void* d_out,
                              int out_size, void* d_ws, size_t ws_size, hipStream_t stream) {
  const float* x = (const float*)d_in[0];
  const float* ft_w = (const float*)d_in[1];
  const float* ft_b = (const float*)d_in[2];
  const float* ln_g = (const float*)d_in[3];
  const float* ln_b = (const float*)d_in[4];
  const float* exc = (const float*)d_in[5];
  const float* qkv_w = (const float*)d_in[6];
  const float* qkv_b = (const float*)d_in[7];
  const float* op_w = (const float*)d_in[8];
  const float* op_b = (const float*)d_in[9];

  char* ws = (char*)d_ws;
  const size_t MB = 1024ull * 1024ull;
  // peak footprint 154 MB (sc reuses x_b/g/u, all dead by attention time).
  bf16* ftw_b = (bf16*)(ws + 0);                  // 1 MB
  bf16* weff = (bf16*)(ws + 1 * MB);              // 4 MB (q,k rows 0:1024; W_v2 rows 1024:2048)
  bf16* opw_b = (bf16*)(ws + 5 * MB);             // 2 MB
  bf16* wvT = (bf16*)(ws + 7 * MB);               // 2 MB
  float* beff = (float*)(ws + 9 * MB);            // 8 KB
  float* cost = (float*)(ws + 9 * MB + 8192);     // 4 KB
  float* sint = (float*)(ws + 9 * MB + 12288);    // 4 KB
  float* lcos = (float*)(ws + 9 * MB + 16384);    // 2 KB
  float* lsin = (float*)(ws + 9 * MB + 18432);    // 2 KB
  bf16* x_b = (bf16*)(ws + 10 * MB);              // 16 MB, dead after stage A
  bf16* gbuf = (bf16*)(ws + 26 * MB);             // 32 MB, dead after LN
  bf16* ubuf = (bf16*)(ws + 58 * MB);             // 32 MB, dead after QKV
  bf16* qk = (bf16*)(ws + 90 * MB);               // 32 MB (16384 x [q|k])
  bf16* v2T = (bf16*)(ws + 122 * MB);             // 32 MB (4 x 1024 x 4096)
  bf16* sc = (bf16*)(ws + 10 * MB);               // 64 MB (2-batch scores; reuse x_b/g)

  cast4_f2b<<<512, 256, 0, stream>>>(ft_w, ftw_b, 131072);
  cast4_f2b<<<1024, 256, 0, stream>>>(op_w, opw_b, 262144);
  cast4_f2b<<<2048, 256, 0, stream>>>(x, x_b, 2097152);
  fold_qkv<<<8192, 256, 0, stream>>>(qkv_w, qkv_b, weff, wvT, beff);
  bias_fold<<<4, 256, 0, stream>>>(op_w, qkv_b, beff);
  tables_kernel<<<4, 256, 0, stream>>>(cost, sint, lcos, lsin, exc);

  // W_v2 = op_w @ W_v  -> weff rows 1024:2048   (A=op_w 1024x1024, B=wvT: B[j,t]=W_v[t,j])
  gemm_bt<0><<<dim3(8, 8), 256, 0, stream>>>(opw_b, wvT, weff + 1024 * 1024, nullptr, nullptr,
                                             1024, 1024, 1024, 1024, 1.0f, 0, 0, 0);
  // stage A: g = gelu(x @ ft_w^T + ft_b)
  gemm_bt<1><<<dim3(8, 128), 256, 0, stream>>>(x_b, ftw_b, gbuf, nullptr, ft_b, 512, 512, 512,
                                               1024, 1.0f, 0, 0, 0);
  // LN + phase -> u
  ln_phase_kernel<<<16384, 256, 0, stream>>>(gbuf, ubuf, ln_g, ln_b, lcos, lsin, cost, sint);
  // [qk | V2] = u @ weff^T + beff ; cols 0:1024 -> qk, cols 1024:2048 -> v2T (transposed)
  gemm_bt<4><<<dim3(16, 128), 256, 0, stream>>>(ubuf, weff, qk, v2T, beff, 1024, 1024, 1024,
                                                1024, 1.0f, 0, 0, 0);

  float* out0 = (float*)d_out;
  float* out1 = out0 + 8388608LL;
  for (int p = 0; p < 2; ++p) {
    const bf16* qbase = qk + (long long)(2 * p) * 4096 * 1024;
    // S = (q k^T) * D^-0.5, batches 2p,2p+1
    gemm_bt<2><<<dim3(32, 32, 2), 256, 0, stream>>>(qbase, qbase + 512, sc, nullptr, nullptr,
                                                    512, 1024, 1024, 4096, 0.04419417382415922f,
                                                    4096LL * 1024, 4096LL * 1024,
                                                    4096LL * 4096);
    softmax_kernel<<<8192, 256, 0, stream>>>(sc);
    // out = P @ V2 + op_b, fp32 split directly into d_out
    gemm_bt<3><<<dim3(8, 32, 2), 256, 0, stream>>>(
        sc, v2T + (long long)(2 * p) * 1024 * 4096, out0 + (long long)(2 * p) * 4096 * 512,
        out1 + (long long)(2 * p) * 4096 * 512, op_b, 4096, 4096, 4096, 0, 1.0f,
        16777216LL, 4194304LL, 4096LL);
  }
  (void)in_sizes;
  (void)n_in;
  (void)out_size;
  (void)ws_size;
}

// Round 3
// 532.543 us; speedup vs baseline: 1.3972x; 1.1467x over previous
//
#include <hip/hip_runtime.h>
#include <hip/hip_bf16.h>
#include <math.h>

// QuantumLLM fused pipeline, round 3: 256x256 8-phase GEMM engine (T2+T3+T4+T5).
// Algebra (proven rounds 1-2): qkv fold K3072->1024 / 4 of 6 blocks; coll==1 const
// excitation; op_w folded into V (softmax rows sum to 1) so PV writes d_out directly.
// New: all big GEMMs on the 8-phase 256^2 engine; PV split-K z=4 (2 batches x 2
// k-chunks) + fp32 partial + combine so its grid fills all 256 CUs.

#define TWO_PI_F 6.283185307179586f

typedef __attribute__((ext_vector_type(4))) float f32x4;
typedef __attribute__((ext_vector_type(8))) short bf16x8;
typedef __attribute__((ext_vector_type(4))) unsigned short u16x4;
typedef __hip_bfloat16 bf16;

__device__ __forceinline__ void gl_lds16(const void* g, void* l) {
  __builtin_amdgcn_global_load_lds((const __attribute__((address_space(1))) void*)g,
                                   (__attribute__((address_space(3))) void*)l, 16, 0, 0);
}
__device__ __forceinline__ unsigned short f2bf_bits(float f) {
  union { __hip_bfloat16 h; unsigned short u; } cv;
  cv.h = __float2bfloat16(f);
  return cv.u;
}
__device__ __forceinline__ float bf_bits2f(unsigned short b) {
  union { unsigned int u; float f; } cv;
  cv.u = ((unsigned int)b) << 16;
  return cv.f;
}

#define BAR8()                          \
  asm volatile("" ::: "memory");        \
  __builtin_amdgcn_s_barrier();         \
  asm volatile("" ::: "memory")
#define WAITV4() asm volatile("s_waitcnt vmcnt(4)" ::: "memory")

// ============ 8-phase 256x256 GEMM: C = epi(A * B^T * scale + bias) ============
// A: Mx K (lda), B: N x K (ldb), bf16 row-major. BM=BN=256, BK=64, 512 thr, 8 waves
// (2M x 4N), per-wave 128x64 out. LDS 128 KiB: 2 bufs x (A 256x64 + B 256x64) bf16,
// XOR-swizzled (byte ^= (row&7)<<4) with pre-swizzled global staging source.
// EPI: 0 bias+bf16; 1 bias+gelu+bf16; 2 scale+bf16 (z: batch); 3 PV split-K
//      (z = kchunk*2 + batch; chunk0: +bias, split fp32 out; chunk1: fp32 partial);
// 4 qkv (col<1024 -> qk, else v2T transposed packed).
template <int EPI>
__global__ __launch_bounds__(512, 2) void gemm8p(
    const bf16* __restrict__ A, const bf16* __restrict__ B, void* __restrict__ C,
    void* __restrict__ Cx, const float* __restrict__ bias, int K, int lda, int ldb, int ldc,
    float scale, long long zsa, long long zsb, long long zsc, float* __restrict__ P0,
    float* __restrict__ P1) {
  __shared__ __align__(16) char lds[131072];
  const int tid = threadIdx.x;
  const int lane = tid & 63, wid = tid >> 6;
  const int wm = wid >> 2, wn = wid & 3;

  // XCD-bijective block swizzle (m204)
  const int gx = gridDim.x, gy = gridDim.y, gz = gridDim.z;
  int flat = blockIdx.x + gx * (blockIdx.y + gy * blockIdx.z);
  {
    const int nwg = gx * gy * gz;
    const int q = nwg >> 3, r = nwg & 7;
    const int x = flat & 7, loc = flat >> 3;
    flat = (x < r ? x * (q + 1) : r * (q + 1) + (x - r) * q) + loc;
  }
  const int bx = flat % gx;
  const int by = (flat / gx) % gy;
  const int bz = flat / (gx * gy);
  const int bm = by * 256, bn = bx * 256;

  const bf16 *Az, *Bz;
  if constexpr (EPI == 3) {
    const int b = bz & 1, c = bz >> 1;
    Az = A + (long long)b * zsa + c * 2048;
    Bz = B + (long long)b * zsb + c * 2048;
  } else {
    Az = A + (long long)bz * zsa;
    Bz = B + (long long)bz * zsb;
  }

  f32x4 acc[8][4];
#pragma unroll
  for (int i = 0; i < 8; ++i)
#pragma unroll
    for (int j = 0; j < 4; ++j) acc[i][j] = (f32x4){0.f, 0.f, 0.f, 0.f};

  bf16x8 afr[8][2];  // m-slot 0..7, kk 0..1 (all 16 live P1..P4)
  bf16x8 bfr[2][2];  // n-pair slot, kk

  // ---- staging constants (write side of the involution) ----
  const int srow = wid * 16 + (lane >> 3);      // + l*8 + h*128
  const int sslot = (lane & 7) ^ (lane >> 3);   // logical 16B k-slot
  const int sldsb = wid * 2048 + lane * 16;     // + l*1024 + h*16384 + region

  auto STG = [&](int isA, int buf, int h, int kt) {
#pragma unroll
    for (int l = 0; l < 2; ++l) {
      const int row = h * 128 + srow + l * 8;
      const bf16* src = isA ? Az : Bz;
      const int ld = isA ? lda : ldb;
      const int r0 = isA ? bm : bn;
      const long long g = (long long)(r0 + row) * ld + (long long)kt * 64 + sslot * 8;
      gl_lds16(src + g, &lds[buf * 65536 + (isA ? 0 : 32768) + h * 16384 + sldsb + l * 1024]);
    }
  };

  // ---- ds-read constants (read side, same involution) ----
  const int rAb = (wm * 128 + (lane & 15)) * 128;  // A row byte base
  const int cBb = (wn * 64 + (lane & 15)) * 128;   // B col byte base
  const int swzr = (lane & 7) << 4;
  const int kbs = (lane >> 4) << 4;
  const int cby0 = (0 + kbs) ^ swzr;
  const int cby1 = (64 + kbs) ^ swzr;

  auto LDA4 = [&](int buf, int i0) {
    const char* base = &lds[buf * 65536] + rAb;
#pragma unroll
    for (int t = 0; t < 4; ++t) {
      afr[i0 + t][0] = *(const bf16x8*)(base + (i0 + t) * 2048 + cby0);
      afr[i0 + t][1] = *(const bf16x8*)(base + (i0 + t) * 2048 + cby1);
    }
  };
  auto LDB2 = [&](int buf, int j0) {
    const char* base = &lds[buf * 65536 + 32768] + cBb;
#pragma unroll
    for (int t = 0; t < 2; ++t) {
      bfr[t][0] = *(const bf16x8*)(base + (j0 + t) * 2048 + cby0);
      bfr[t][1] = *(const bf16x8*)(base + (j0 + t) * 2048 + cby1);
    }
  };
  auto MFMA16 = [&](int i0, int j0) {
    __builtin_amdgcn_s_setprio(1);
#pragma unroll
    for (int t = 0; t < 4; ++t)
#pragma unroll
      for (int u = 0; u < 2; ++u)
#pragma unroll
        for (int kk = 0; kk < 2; ++kk)
          acc[i0 + t][j0 + u] = __builtin_amdgcn_mfma_f32_16x16x32_bf16(
              afr[i0 + t][kk], bfr[u][kk], acc[i0 + t][j0 + u], 0, 0, 0);
    __builtin_amdgcn_s_setprio(0);
  };

  const int nkt = K >> 6;
  const int nit = nkt >> 1;

  // prologue: Kt0 full -> buf0; Kt1 A-halves -> buf1  (12 loads/wave)
  STG(1, 0, 0, 0);
  STG(1, 0, 1, 0);
  STG(0, 0, 0, 0);
  STG(0, 0, 1, 0);
  STG(0, 1, 0, 1);
  STG(0, 1, 1, 1);
  WAITV4();
  BAR8();

  for (int i = 0; i < nit; ++i) {
    const int k1 = 2 * i + 1;
    const int k2t = 2 * i + 2, k3t = 2 * i + 3;
    const int k2 = (k2t < nkt) ? k2t : 0;
    const int k3 = (k3t < nkt) ? k3t : 0;
    // P1: reads buf0 A[m0-3],B[n0-1]; stage buf1 B-half0 (kt k1)
    LDA4(0, 0);
    LDB2(0, 0);
    STG(1, 1, 0, k1);
    BAR8();
    MFMA16(0, 0);
    BAR8();
    // P2: reads buf0 A[m4-7]; stage buf1 B-half1
    LDA4(0, 4);
    STG(1, 1, 1, k1);
    BAR8();
    MFMA16(4, 0);
    BAR8();
    // P3: reads buf0 B[n2-3]; stage buf0 A-half0 (kt k2)
    LDB2(0, 2);
    STG(0, 0, 0, k2);
    BAR8();
    MFMA16(0, 2);
    BAR8();
    // P4: stage buf0 A-half1; counted wait
    STG(0, 0, 1, k2);
    BAR8();
    MFMA16(4, 2);
    WAITV4();
    BAR8();
    // P5: reads buf1 A[m0-3],B[n0-1]; stage buf0 B-half0 (kt k2)
    LDA4(1, 0);
    LDB2(1, 0);
    STG(1, 0, 0, k2);
    BAR8();
    MFMA16(0, 0);
    BAR8();
    // P6: reads buf1 A[m4-7]; stage buf0 B-half1
    LDA4(1, 4);
    STG(1, 0, 1, k2);
    BAR8();
    MFMA16(4, 0);
    BAR8();
    // P7: reads buf1 B[n2-3]; stage buf1 A-half0 (kt k3)
    LDB2(1, 2);
    STG(0, 1, 0, k3);
    BAR8();
    MFMA16(0, 2);
    BAR8();
    // P8: stage buf1 A-half1; counted wait
    STG(0, 1, 1, k3);
    BAR8();
    MFMA16(4, 2);
    WAITV4();
    BAR8();
  }

  // ---- epilogue ----
#pragma unroll
  for (int i = 0; i < 8; ++i)
#pragma unroll
    for (int j = 0; j < 4; ++j) {
      const int row0 = bm + wm * 128 + i * 16 + ((lane >> 4) << 2);
      const int col = bn + wn * 64 + j * 16 + (lane & 15);
      float v[4];
#pragma unroll
      for (int r = 0; r < 4; ++r) {
        v[r] = acc[i][j][r] * scale;
        if constexpr (EPI == 0 || EPI == 1 || EPI == 4) {
          if (bias) v[r] += bias[col];
        }
        if constexpr (EPI == 1) {
          const float t = v[r];
          float y = 0.7978845608028654f * (t + 0.044715f * t * t * t);
          y = fminf(fmaxf(y, -15.f), 15.f);
          const float e = __expf(2.f * y);
          v[r] = t * e / (1.f + e);
        }
      }
      if constexpr (EPI == 3) {
        const int b = bz & 1, c = bz >> 1;
        if (c == 0) {
          float* dst = (col < 512) ? (float*)C : (float*)Cx;
          const long long rb = zsc + (long long)b * 4096 + row0;
#pragma unroll
          for (int r = 0; r < 4; ++r) dst[(rb + r) * 512 + (col & 511)] = v[r] + bias[col];
        } else {
          float* dst = b ? P1 : P0;
#pragma unroll
          for (int r = 0; r < 4; ++r) dst[(long long)(row0 + r) * 1024 + col] = v[r];
        }
      } else if constexpr (EPI == 4) {
        if (col < 1024) {
          bf16* cc = (bf16*)C;
#pragma unroll
          for (int r = 0; r < 4; ++r)
            cc[(long long)(row0 + r) * 1024 + col] = __float2bfloat16(v[r]);
        } else {
          const int d = col - 1024, b = row0 >> 12, mm = row0 & 4095;
          u16x4 w;
#pragma unroll
          for (int r = 0; r < 4; ++r) w[r] = f2bf_bits(v[r]);
          *(u16x4*)((unsigned short*)Cx + ((long long)(b * 1024 + d)) * 4096 + mm) = w;
        }
      } else if constexpr (EPI == 2) {
        bf16* cc = (bf16*)C + (long long)bz * zsc;
#pragma unroll
        for (int r = 0; r < 4; ++r)
          cc[(long long)(row0 + r) * ldc + col] = __float2bfloat16(v[r]);
      } else {
        bf16* cc = (bf16*)C;
#pragma unroll
        for (int r = 0; r < 4; ++r)
          cc[(long long)(row0 + r) * ldc + col] = __float2bfloat16(v[r]);
      }
    }
}

// ---------------- combine: out += partial (one batch-pair) ----------------
__global__ __launch_bounds__(256) void combine_kernel(const float* __restrict__ p0,
                                                      const float* __restrict__ p1,
                                                      float* __restrict__ out0,
                                                      float* __restrict__ out1) {
  const int idx = blockIdx.x * 256 + threadIdx.x;  // 0..2M-1 (x4 floats)
  const int b = idx >> 20;
  const int rem = idx & 1048575;
  const int row = rem >> 8;
  const int c4 = rem & 255;
  const float* p = b ? p1 : p0;
  const f32x4 v = *(const f32x4*)(p + (long long)row * 1024 + c4 * 4);
  float* dst = (c4 < 128) ? out0 : out1;
  const long long o = ((long long)(b * 4096 + row)) * 512 + (c4 & 127) * 4;
  f32x4 d = *(f32x4*)(dst + o);
  d += v;
  *(f32x4*)(dst + o) = d;
}

// ---------------- LayerNorm + phase ops: g(row,1024) -> u(row,1024) ----------------
__global__ __launch_bounds__(256) void ln_phase_kernel(
    const bf16* __restrict__ g, bf16* __restrict__ u, const float* __restrict__ ln_g,
    const float* __restrict__ ln_b, const float* __restrict__ lcos,
    const float* __restrict__ lsin, const float* __restrict__ cost,
    const float* __restrict__ sint) {
  __shared__ float sg[1024];
  __shared__ float red[4];
  const int tid = threadIdx.x;
  const int lane = tid & 63, wid = tid >> 6;
  const long long row = blockIdx.x;
  const bf16* gr = g + row * 1024;

  const u16x4 raw = *(const u16x4*)(gr + tid * 4);
  float lv[4];
  float lsum = 0.f;
#pragma unroll
  for (int e = 0; e < 4; ++e) {
    lv[e] = bf_bits2f(raw[e]);
    lsum += lv[e];
  }
  *(f32x4*)&sg[tid * 4] = *(f32x4*)lv;
#pragma unroll
  for (int off = 32; off > 0; off >>= 1) lsum += __shfl_xor(lsum, off);
  if (lane == 0) red[wid] = lsum;
  __syncthreads();
  const float mu = (red[0] + red[1] + red[2] + red[3]) * (1.0f / 1024.0f);
  __syncthreads();
  float lvar = 0.f;
#pragma unroll
  for (int e = 0; e < 4; ++e) {
    const float d = lv[e] - mu;
    lvar += d * d;
  }
#pragma unroll
  for (int off = 32; off > 0; off >>= 1) lvar += __shfl_xor(lvar, off);
  if (lane == 0) red[wid] = lvar;
  __syncthreads();
  const float var = (red[0] + red[1] + red[2] + red[3]) * (1.0f / 1024.0f);
  const float rs = rsqrtf(var + 1e-5f);

#pragma unroll
  for (int kk = 0; kk < 2; ++kk) {
    const int p = tid + kk * 256;
    const float rp = (sg[p] - mu) * rs * ln_g[p] + ln_b[p];
    const float ip = (sg[p + 512] - mu) * rs * ln_g[p + 512] + ln_b[p + 512];
    const float ang = atan2f(ip + 1e-8f, rp + 1e-8f);
    int idx = (int)((ang / TWO_PI_F) * 1023.0f);
    idx = idx < 0 ? idx + 1024 : idx;
    float real = rp * cost[idx];
    float imag = ip * sint[idx];
    const float nrm = rsqrtf(real * real + imag * imag + 1e-8f) * 0.044194173824159216f;
    real *= nrm;
    imag *= nrm;
    const float amp = sqrtf(real * real + imag * imag + 1e-8f);
    const float coll = (amp < 0.1f) ? 1.0f : 0.0f;
    real += coll * lcos[p];
    imag += coll * lsin[p];
    const float n2 = rsqrtf(real * real + imag * imag + 1e-8f);
    u[row * 1024 + p] = __float2bfloat16(real * n2);
    u[row * 1024 + 512 + p] = __float2bfloat16(imag * n2);
  }
}

// ---------------- rowwise softmax in place on bf16 scores (row = 4096) ----------------
__global__ __launch_bounds__(256) void softmax_kernel(bf16* __restrict__ s) {
  __shared__ float ss[4096];
  __shared__ float red[4];
  const int tid = threadIdx.x;
  const int lane = tid & 63, wid = tid >> 6;
  bf16* sr = s + (long long)blockIdx.x * 4096;
  float mx = -3.0e38f;
#pragma unroll
  for (int k = 0; k < 4; ++k) {
    const int base = (k * 256 + tid) * 4;
    const u16x4 raw = *(const u16x4*)(sr + base);
    f32x4 f;
#pragma unroll
    for (int e = 0; e < 4; ++e) {
      f[e] = bf_bits2f(raw[e]);
      mx = fmaxf(mx, f[e]);
    }
    *(f32x4*)&ss[base] = f;
  }
#pragma unroll
  for (int off = 32; off > 0; off >>= 1) mx = fmaxf(mx, __shfl_xor(mx, off));
  if (lane == 0) red[wid] = mx;
  __syncthreads();
  mx = fmaxf(fmaxf(red[0], red[1]), fmaxf(red[2], red[3]));
  __syncthreads();
  float sum = 0.f;
#pragma unroll
  for (int k = 0; k < 4; ++k) {
    const int base = (k * 256 + tid) * 4;
    f32x4 f = *(f32x4*)&ss[base];
#pragma unroll
    for (int e = 0; e < 4; ++e) {
      f[e] = __expf(f[e] - mx);
      sum += f[e];
    }
    *(f32x4*)&ss[base] = f;
  }
#pragma unroll
  for (int off = 32; off > 0; off >>= 1) sum += __shfl_xor(sum, off);
  if (lane == 0) red[wid] = sum;
  __syncthreads();
  const float inv = 1.0f / (red[0] + red[1] + red[2] + red[3]);
#pragma unroll
  for (int k = 0; k < 4; ++k) {
    const int base = (k * 256 + tid) * 4;
    const f32x4 f = *(f32x4*)&ss[base];
    u16x4 w;
#pragma unroll
    for (int e = 0; e < 4; ++e) w[e] = f2bf_bits(f[e] * inv);
    *(u16x4*)(sr + base) = w;
  }
}

// ---------------- prep ----------------
__global__ void cast4_f2b(const float* __restrict__ in, bf16* __restrict__ out, long long n4) {
  long long i = (long long)blockIdx.x * blockDim.x + threadIdx.x;
  const long long stride = (long long)gridDim.x * blockDim.x;
  for (; i < n4; i += stride) {
    const f32x4 f = *(const f32x4*)(in + i * 4);
    u16x4 w;
#pragma unroll
    for (int e = 0; e < 4; ++e) w[e] = f2bf_bits(f[e]);
    *(u16x4*)((unsigned short*)out + i * 4) = w;
  }
}

__global__ void fold_qkv(const float* __restrict__ w, const float* __restrict__ b,
                         bf16* __restrict__ weff, bf16* __restrict__ wvT,
                         float* __restrict__ beff) {
  const int i = blockIdx.x * blockDim.x + threadIdx.x;
  if (i < 2048 * 1024) {
    const int o = i >> 10, j = i & 1023;
    if (o < 1024) {
      const int so = (o < 512) ? o : o + 512;
      const float* wr = w + (long long)so * 3072;
      weff[i] = __float2bfloat16(wr[j] + wr[1024 + j] + wr[2048 + j]);
      if (j == 0) beff[o] = b[so];
    } else {
      const int t = o - 1024;
      const float* wr = w + (long long)(2048 + t) * 3072;
      wvT[(long long)j * 1024 + t] = __float2bfloat16(wr[j] + wr[1024 + j] + wr[2048 + j]);
    }
  }
}

__global__ void bias_fold(const float* __restrict__ op_w, const float* __restrict__ qkv_b,
                          float* __restrict__ beff) {
  const int o = blockIdx.x * blockDim.x + threadIdx.x;
  if (o < 1024) {
    const float* wr = op_w + (long long)o * 1024;
    float s = 0.f;
    for (int t = 0; t < 1024; ++t) s += wr[t] * qkv_b[2048 + t];
    beff[1024 + o] = s;
  }
}

__global__ void tables_kernel(float* __restrict__ cost, float* __restrict__ sint,
                              float* __restrict__ lcos, float* __restrict__ lsin,
                              const float* __restrict__ exc) {
  const int i = blockIdx.x * blockDim.x + threadIdx.x;
  const double step = 6.283185307179586 / 1023.0;
  if (i < 1024) {
    const float a = (float)((double)i * step);
    cost[i] = cosf(a);
    sint[i] = sinf(a);
  }
  if (i < 512) {
    const float el = ((float)i / 511.0f) * TWO_PI_F;
    const float m = fmodf(el, TWO_PI_F);
    int li = (int)((m / TWO_PI_F) * 1024.0f);
    li = min(max(li, 0), 1023);
    const float a = (float)((double)li * step);
    lcos[i] = cosf(a) * exc[0];
    lsin[i] = sinf(a) * exc[0];
  }
}

extern "C" void kernel_launch(void* const* d_in, const int* in_sizes, int n_in, void* d_out,
                              int out_size, void* d_ws, size_t ws_size, hipStream_t stream) {
  const float* x = (const float*)d_in[0];
  const float* ft_w = (const float*)d_in[1];
  const float* ft_b = (const float*)d_in[2];
  const float* ln_g = (const float*)d_in[3];
  const float* ln_b = (const float*)d_in[4];
  const float* exc = (const float*)d_in[5];
  const float* qkv_w = (const float*)d_in[6];
  const float* qkv_b = (const float*)d_in[7];
  const float* op_w = (const float*)d_in[8];
  const float* op_b = (const float*)d_in[9];

  char* ws = (char*)d_ws;
  const size_t MB = 1024ull * 1024ull;
  // layout (peak 170 MB):
  bf16* ftw_b = (bf16*)(ws + 0);                // 1 MB
  bf16* weff = (bf16*)(ws + 1 * MB);            // 4 MB (q,k rows 0:1024; W_v2 1024:2048)
  bf16* opw_b = (bf16*)(ws + 5 * MB);           // 2 MB
  bf16* wvT = (bf16*)(ws + 7 * MB);             // 2 MB
  float* beff = (float*)(ws + 9 * MB);          // 8 KB
  float* cost = (float*)(ws + 9 * MB + 8192);
  float* sint = (float*)(ws + 9 * MB + 12288);
  float* lcos = (float*)(ws + 9 * MB + 16384);
  float* lsin = (float*)(ws + 9 * MB + 18432);
  bf16* v2T = (bf16*)(ws + 10 * MB);            // 32 MB (4 x 1024 x 4096)
  bf16* qk = (bf16*)(ws + 42 * MB);             // 32 MB (16384 x [q|k])
  bf16* x_b = (bf16*)(ws + 74 * MB);            // 16 MB, dead after stage A
  bf16* gbuf = (bf16*)(ws + 90 * MB);           // 32 MB, dead after LN
  bf16* ubuf = (bf16*)(ws + 122 * MB);          // 32 MB, dead after QKV
  bf16* sc = (bf16*)(ws + 74 * MB);             // 64 MB scores (reuses x_b/gbuf/ubuf head)
  float* part0 = (float*)(ws + 138 * MB);       // 16 MB
  float* part1 = (float*)(ws + 154 * MB);       // 16 MB

  cast4_f2b<<<512, 256, 0, stream>>>(ft_w, ftw_b, 131072);
  cast4_f2b<<<1024, 256, 0, stream>>>(op_w, opw_b, 262144);
  cast4_f2b<<<2048, 256, 0, stream>>>(x, x_b, 2097152);
  fold_qkv<<<8192, 256, 0, stream>>>(qkv_w, qkv_b, weff, wvT, beff);
  bias_fold<<<4, 256, 0, stream>>>(op_w, qkv_b, beff);
  tables_kernel<<<4, 256, 0, stream>>>(cost, sint, lcos, lsin, exc);

  // W_v2 = op_w @ W_v -> weff rows 1024:2048
  gemm8p<0><<<dim3(4, 4), 512, 0, stream>>>(opw_b, wvT, weff + 1024 * 1024, nullptr, nullptr,
                                            1024, 1024, 1024, 1024, 1.0f, 0, 0, 0, nullptr,
                                            nullptr);
  // stage A: g = gelu(x @ ft_w^T + ft_b)
  gemm8p<1><<<dim3(4, 64), 512, 0, stream>>>(x_b, ftw_b, gbuf, nullptr, ft_b, 512, 512, 512,
                                             1024, 1.0f, 0, 0, 0, nullptr, nullptr);
  // LN + phase -> u
  ln_phase_kernel<<<16384, 256, 0, stream>>>(gbuf, ubuf, ln_g, ln_b, lcos, lsin, cost, sint);
  // [qk | V2] = u @ weff^T + beff ; cols 0:1024 -> qk, 1024:2048 -> v2T transposed
  gemm8p<4><<<dim3(8, 64), 512, 0, stream>>>(ubuf, weff, qk, v2T, beff, 1024, 1024, 1024,
                                             1024, 1.0f, 0, 0, 0, nullptr, nullptr);

  float* out0 = (float*)d_out;
  float* out1 = out0 + 8388608LL;
  for (int p = 0; p < 2; ++p) {
    const bf16* qbase = qk + (long long)(2 * p) * 4096 * 1024;
    // S = (q k^T) * D^-0.5, batches 2p, 2p+1
    gemm8p<2><<<dim3(16, 16, 2), 512, 0, stream>>>(
        qbase, qbase + 512, sc, nullptr, nullptr, 512, 1024, 1024, 4096,
        0.04419417382415922f, 4096LL * 1024, 4096LL * 1024, 4096LL * 4096, nullptr, nullptr);
    softmax_kernel<<<8192, 256, 0, stream>>>(sc);
    // out = P @ V2 + op_b; split-K z=4 (2 batches x 2 k-chunks), chunk1 -> partial
    gemm8p<3><<<dim3(4, 16, 4), 512, 0, stream>>>(
        sc, v2T + (long long)(2 * p) * 1024 * 4096, out0, out1, op_b, 2048, 4096, 4096, 0,
        1.0f, 4096LL * 4096, 1024LL * 4096, (long long)(2 * p) * 4096, part0, part1);
    combine_kernel<<<8192, 256, 0, stream>>>(part0, part1, out0 + (long long)(2 * p) * 4096 * 512,
                                             out1 + (long long)(2 * p) * 4096 * 512);
  }
  (void)in_sizes;
  (void)n_in;
  (void)out_size;
  (void)ws_size;
}